// Round 11
// baseline (759.148 us; speedup 1.0000x reference)
//
#include <hip/hip_runtime.h>
#include <math.h>

#define NB 64      // batch
#define TTX 256    // text timesteps
#define TTP 16     // topic timesteps
#define EE 300     // embedding dim
#define HH 512     // hidden
#define SENT16 0x7FC1u        // bf16 NaN-payload sentinel (real h never NaN)
#define SENT32 0x7FC17FC1u

typedef __attribute__((ext_vector_type(4))) float f32x4;
typedef __attribute__((ext_vector_type(8))) short short8;

__device__ __forceinline__ unsigned short bf16cvt(float f) {
  unsigned u = __float_as_uint(f);
  u += 0x7FFFu + ((u >> 16) & 1u);   // RNE
  return (unsigned short)(u >> 16);
}

// ---------------------------------------------------------------------------
// prep: (a) poison the bf16 h-ring (every call: graph-replay deterministic),
// (b) build Bt in FRAGMENT order (unchanged from round 10, verified)
// ---------------------------------------------------------------------------
__global__ __launch_bounds__(256) void sd_prep(
    const float* __restrict__ tWz, const float* __restrict__ tWo,
    const float* __restrict__ pWz, const float* __restrict__ pWo,
    unsigned short* __restrict__ Bt, unsigned* __restrict__ ring32)
{
  const int i = blockIdx.x * 256 + threadIdx.x;   // [0, 655360)
  if (i < 4 * NB * HH / 2) ring32[i] = SENT32;    // 65536 u32 = whole ring
  const int half = 327680;
  const int j = (i < half) ? i : i - half;
  const int e    = j & 7;
  const int lane = (j >> 3) & 63;
  const int kc   = (j >> 9) % 10;
  const int tile = (j >> 9) / 10;
  const int k = kc * 32 + 8 * (lane >> 4) + e;
  const int c = tile * 16 + (lane & 15);
  const float* W = (i < half) ? ((c < 512) ? tWz : tWo)
                              : ((c < 512) ? pWz : pWo);
  const float v = (k < 300) ? W[(size_t)k * HH + (c & 511)] : 0.f;
  Bt[i] = bf16cvt(v);
}

// ---------------------------------------------------------------------------
// xproj via MFMA bf16 (unchanged from round 10, verified)
// ---------------------------------------------------------------------------
__global__ __launch_bounds__(256) void sd_xproj_mfma(
    const int* __restrict__ text_idx, const int* __restrict__ topic_idx,
    const float* __restrict__ emb,
    const unsigned short* __restrict__ bt_text, const unsigned short* __restrict__ bt_topic,
    const float* __restrict__ tbz, const float* __restrict__ tbo,
    const float* __restrict__ pbz, const float* __restrict__ pbo,
    float* __restrict__ xp_text, float* __restrict__ xp_topic)
{
  __shared__ alignas(16) unsigned short Als[64 * 328];
  __shared__ int tok[64];

  const bool is_text = blockIdx.x < TTX;
  const int t   = is_text ? blockIdx.x : blockIdx.x - TTX;
  const int T   = is_text ? TTX : TTP;
  const int* idx = is_text ? text_idx : topic_idx;
  const unsigned short* Bt = is_text ? bt_text : bt_topic;
  const float* bz = is_text ? tbz : pbz;
  const float* bo = is_text ? tbo : pbo;
  float* xp = is_text ? xp_text : xp_topic;

  const int tid = threadIdx.x;
  const int c0  = blockIdx.y * 256;

  if (tid < 64) tok[tid] = idx[tid * T + t];
  __syncthreads();

  {
    const int m  = tid >> 2;
    const int qt = tid & 3;
    const float* er = emb + (size_t)tok[m] * EE;
    unsigned short* ar = Als + m * 328;
    for (int j = qt; j < 75; j += 4) {
      const float4 v = *(const float4*)(er + 4 * j);
      ushort4 o;
      o.x = bf16cvt(v.x); o.y = bf16cvt(v.y);
      o.z = bf16cvt(v.z); o.w = bf16cvt(v.w);
      *(ushort4*)(ar + 4 * j) = o;
    }
    if (qt == 0) {
      for (int k = 300; k < 328; ++k) ar[k] = 0;
    }
  }
  __syncthreads();

  const int w  = tid >> 6;
  const int l  = tid & 63;
  const int lr = l & 15;
  const int lg = l >> 4;
  const int tile0 = blockIdx.y * 16 + w * 4;   // this wave's first col-tile

  f32x4 acc[4][4];
#pragma unroll
  for (int ms = 0; ms < 4; ++ms)
#pragma unroll
    for (int ns = 0; ns < 4; ++ns)
      acc[ms][ns] = (f32x4){0.f, 0.f, 0.f, 0.f};

#pragma unroll 2
  for (int kc = 0; kc < 10; ++kc) {
    short8 bfr[4];
#pragma unroll
    for (int ns = 0; ns < 4; ++ns)
      bfr[ns] = *reinterpret_cast<const short8*>(
          Bt + (((size_t)(tile0 + ns) * 10 + kc) * 64 + l) * 8);
    short8 afr[4];
#pragma unroll
    for (int ms = 0; ms < 4; ++ms)
      afr[ms] = *reinterpret_cast<const short8*>(Als + (ms * 16 + lr) * 328 + kc * 32 + 8 * lg);
#pragma unroll
    for (int ms = 0; ms < 4; ++ms)
#pragma unroll
      for (int ns = 0; ns < 4; ++ns)
        acc[ms][ns] = __builtin_amdgcn_mfma_f32_16x16x32_bf16(afr[ms], bfr[ns], acc[ms][ns], 0, 0, 0);
  }

#pragma unroll
  for (int ns = 0; ns < 4; ++ns) {
    const int cg = c0 + w * 64 + ns * 16 + lr;
    const float bias = (cg < 512) ? bz[cg] : bo[cg - 512];
#pragma unroll
    for (int ms = 0; ms < 4; ++ms) {
#pragma unroll
      for (int r = 0; r < 4; ++r) {
        const int row = ms * 16 + lg * 4 + r;
        xp[((size_t)t * 64 + row) * 1024 + cg] = acc[ms][ns][r] + bias;
      }
    }
  }
}

// ---------------------------------------------------------------------------
// Persistent recurrence kernel — r10 structure with HALVED exchange radius:
//   128 blocks = 16 batch-groups x 8 dim-slices (64 dims each).
//   Mechanism targeted: consumer poll completes at the max over PRODUCER
//   count store-completions (straggler) and MALL poll congestion; both
//   halve with 8 producers/consumers per group instead of 16.
//   Per block: wave wv = k-eighth, 8 n-subtiles (2 gates x 64 dims),
//   16 MFMAs/step. Writers = 256 threads (4 rows x 64 dims), identical
//   per-thread tail work as r10. Arithmetic bit-identical to r10 (same
//   k-split, same 8-partial reduction order, same bf16 fragments).
//   Ring protocol / vmcnt(1) poison accounting unchanged (r9/r10-verified).
// ---------------------------------------------------------------------------
__global__ __launch_bounds__(512) void sd_recur(
    const float* __restrict__ tWz, const float* __restrict__ tWo,
    const float* __restrict__ pWz, const float* __restrict__ pWo,
    const float* __restrict__ xp_text, const float* __restrict__ xp_topic,
    float* __restrict__ text_out, unsigned short* __restrict__ hring,
    float* __restrict__ topic_h)
{
  __shared__ alignas(16) unsigned short h_bf[2][2080];  // bf16 h, [4 rows][520]
  __shared__ alignas(16) float red[2][4096];            // [8 wv][4 row][128 col]

  const int tid = threadIdx.x;
  const int bid = blockIdx.x;
  const int slice = bid & 7;       // dim slice 0..7 (64 dims)
  const int g = bid >> 3;          // batch group 0..15
  const int b0 = g * 4;
  const int c_base = slice * 64;

  const int wv = tid >> 6;         // wave id = k-eighth (0..7)
  const int lane = tid & 63;
  const int lg = lane >> 4;        // k-slot group 0..3
  const int l15 = lane & 15;

  const int bi_w = tid >> 6;       // writer mapping (tid<256): batch row 0..3
  const int dw = tid & 63;         // writer dim offset 0..63

  // writer thread's ring offset within a slot (bf16 units)
  const size_t wslot_off = (size_t)(b0 + bi_w) * HH + c_base + dw;

  int u = 0;  // global step counter across both phases

  for (int ph = 0; ph < 2; ++ph) {
    const float* Wz = ph ? pWz : tWz;
    const float* Wo = ph ? pWo : tWo;
    const float* xp = ph ? xp_topic : xp_text;
    const int T = ph ? TTP : TTX;

    float hprev_r = 0.f;  // writer's own h (fp32-exact), reset per phase

    // --- prep W h-part bf16 B-fragments (once per phase) ----------------
    // ns 0..3 -> gate z dims ns*16+l15; ns 4..7 -> gate o dims (ns-4)*16+l15
    short8 wfrag[8][2];
#pragma unroll
    for (int ns = 0; ns < 8; ++ns) {
      const float* Wg = (ns < 4) ? Wz : Wo;
      const int dim = (ns & 3) * 16 + l15;
#pragma unroll
      for (int kc = 0; kc < 2; ++kc) {
        const int kb = wv * 64 + kc * 32 + 8 * lg;
        short8 f;
#pragma unroll
        for (int e = 0; e < 8; ++e)
          f[e] = (short)bf16cvt(Wg[(size_t)(EE + kb + e) * HH + c_base + dim]);
        wfrag[ns][kc] = f;
      }
    }

    for (int t = 0; t < T; ++t, ++u) {
      const int cur = u & 1;
      const bool do_poll = (u > 0);
      const bool use_h   = (t > 0);

      float xpz = 0.f, xpo = 0.f;
      if (tid < 256) {
        const float* xpr = xp + ((size_t)t * 64 + (b0 + bi_w)) * 1024 + c_base + dw;
        xpz = xpr[0];
        xpo = xpr[512];
      }

      if (do_poll) {
        // block-wide poll-stage: one u64 (4 bf16) per thread, 4 rows x 512
        const unsigned long long* src64 = (const unsigned long long*)
            (hring + (size_t)(u & 3) * NB * HH + (size_t)b0 * HH);
        unsigned long long v;
        for (;;) {
          v = __hip_atomic_load(src64 + tid, __ATOMIC_RELAXED, __HIP_MEMORY_SCOPE_AGENT);
          const unsigned lo = (unsigned)v, hi = (unsigned)(v >> 32);
          if ((lo & 0xFFFFu) != SENT16 && (lo >> 16) != SENT16 &&
              (hi & 0xFFFFu) != SENT16 && (hi >> 16) != SENT16) break;
          __builtin_amdgcn_s_sleep(1);
        }
        *(unsigned long long*)&h_bf[cur][(tid >> 7) * 520 + (tid & 127) * 4] = v;
      }

      __syncthreads();  // whole block's poll complete + stage visible

      // Safe to recycle own stripe of slot (u-1)&3 now.
      if (do_poll && tid < 256 && !(tid & 1))
        __hip_atomic_store((unsigned*)(hring + (size_t)((u - 1) & 3) * NB * HH + wslot_off),
                           SENT32, __ATOMIC_RELAXED, __HIP_MEMORY_SCOPE_AGENT);

      if (use_h) {
        const unsigned short* hb = &h_bf[cur][(lane & 3) * 520 + wv * 64 + 8 * lg];
        const short8 a0 = *reinterpret_cast<const short8*>(hb + 0);
        const short8 a1 = *reinterpret_cast<const short8*>(hb + 32);

        f32x4 acc[8];
#pragma unroll
        for (int ns = 0; ns < 8; ++ns) {
          acc[ns] = (f32x4){0.f, 0.f, 0.f, 0.f};
          acc[ns] = __builtin_amdgcn_mfma_f32_16x16x32_bf16(a0, wfrag[ns][0], acc[ns], 0, 0, 0);
          acc[ns] = __builtin_amdgcn_mfma_f32_16x16x32_bf16(a1, wfrag[ns][1], acc[ns], 0, 0, 0);
        }
        if (lane < 16) {
#pragma unroll
          for (int ns = 0; ns < 8; ++ns)
#pragma unroll
            for (int r = 0; r < 4; ++r)
              red[cur][wv * 512 + r * 128 + ns * 16 + lane] = acc[ns][r];
        }
      }

      __syncthreads();  // partials visible

      if (tid < 256) {
        float zp = 0.f, op = 0.f;
        if (use_h) {
#pragma unroll
          for (int k2 = 0; k2 < 8; ++k2) {
            zp += red[cur][k2 * 512 + bi_w * 128 + dw];        // gate z
            op += red[cur][k2 * 512 + bi_w * 128 + 64 + dw];   // gate o
          }
        }
        const float a = zp + xpz;
        const float z = 1.f / (1.f + __expf(-a));
        const float bv = op + xpo;
        const float ab = fabsf(bv);
        const float e2 = __expf(-2.f * ab);
        const float htl = __builtin_copysignf((1.f - e2) / (1.f + e2), bv);
        const float hn = (1.f - z) * hprev_r + z * htl;
        hprev_r = hn;

        // pack 2 bf16 per lane pair; even thread stores one sc1 dword
        const unsigned short hb16 = bf16cvt(hn);
        const unsigned packed = (unsigned)hb16 |
                                ((unsigned)__shfl_down((int)hb16, 1, 64) << 16);

        // drain everything EXCEPT this step's own poison (per-wave counter)
        asm volatile("s_waitcnt vmcnt(1)" ::: "memory");
        if (!(tid & 1))
          __hip_atomic_store((unsigned*)(hring + (size_t)((u + 1) & 3) * NB * HH + wslot_off),
                             packed, __ATOMIC_RELAXED, __HIP_MEMORY_SCOPE_AGENT);
        if (ph == 0)
          text_out[((size_t)(b0 + bi_w) * TTX + t) * HH + c_base + dw] = hn;
        else if (t == T - 1)
          topic_h[(size_t)(b0 + bi_w) * HH + c_base + dw] = hn;
      }
      // no trailing barrier: 2-deep buffers tolerate one-phase skew
    }
  }
}

// ---------------------------------------------------------------------------
// attention + FC head fused (unchanged from round 9/10, verified)
// ---------------------------------------------------------------------------
__global__ __launch_bounds__(256) void sd_att_fc(
    const float* __restrict__ text_out, const float* __restrict__ topic_h,
    const float* __restrict__ att_W, const float* __restrict__ att_b,
    const float* __restrict__ fc1_W, const float* __restrict__ fc1_b,
    const float* __restrict__ fc2_W, const float* __restrict__ fc2_b,
    float* __restrict__ logits, float* __restrict__ weights_out)
{
  __shared__ alignas(16) float aw[1024];
  __shared__ alignas(16) float th[512];
  __shared__ float sc_s[256];
  __shared__ float sred[256];
  __shared__ float wsh[256];
  __shared__ alignas(16) float feat[1024];
  __shared__ float hid[512];
  const int b = blockIdx.x, tid = threadIdx.x;

  for (int i = tid; i < 1024; i += 256) aw[i] = att_W[i];
  for (int i = tid; i < 512; i += 256) th[i] = topic_h[(size_t)b * HH + i];
  __syncthreads();

  float part = 0.f;
  for (int i = tid; i < 512; i += 256) part += th[i] * aw[512 + i];
  sred[tid] = part;
  __syncthreads();
  for (int s = 128; s > 0; s >>= 1) { if (tid < s) sred[tid] += sred[tid + s]; __syncthreads(); }
  const float cb = sred[0] + att_b[0];
  __syncthreads();

  const int gr = tid >> 5, ln = tid & 31;
  for (int rep = 0; rep < 32; ++rep) {
    const int t = rep * 8 + gr;
    const float* row = text_out + ((size_t)b * TTX + t) * HH;
    float p = 0.f;
#pragma unroll
    for (int j = 0; j < 4; ++j) {
      const float4 v  = *(const float4*)(row + ln * 4 + 128 * j);
      const float4 w4 = *(const float4*)(aw  + ln * 4 + 128 * j);
      p += v.x * w4.x + v.y * w4.y + v.z * w4.z + v.w * w4.w;
    }
#pragma unroll
    for (int o = 16; o > 0; o >>= 1) p += __shfl_xor(p, o, 32);
    if (ln == 0) sc_s[t] = p + cb;
  }
  __syncthreads();

  const float sc = sc_s[tid];
  sred[tid] = sc; __syncthreads();
  for (int s = 128; s > 0; s >>= 1) { if (tid < s) sred[tid] = fmaxf(sred[tid], sred[tid + s]); __syncthreads(); }
  const float m = sred[0];
  __syncthreads();
  const float e = expf(sc - m);
  sred[tid] = e; __syncthreads();
  for (int s = 128; s > 0; s >>= 1) { if (tid < s) sred[tid] += sred[tid + s]; __syncthreads(); }
  const float wv = e / sred[0];
  wsh[tid] = wv;
  weights_out[(size_t)b * TTX + tid] = wv;
  __syncthreads();

  for (int rep = 0; rep < 2; ++rep) {
    const int dcol = rep * 256 + tid;
    float accc = 0.f;
    const float* base = text_out + (size_t)b * TTX * HH + dcol;
    for (int t2 = 0; t2 < TTX; ++t2) accc += wsh[t2] * base[(size_t)t2 * HH];
    feat[dcol] = accc;
  }
  for (int i = tid; i < 512; i += 256) feat[512 + i] = th[i];
  __syncthreads();

  for (int rep = 0; rep < 2; ++rep) {
    const int dcol = rep * 256 + tid;
    float a = fc1_b[dcol];
#pragma unroll 4
    for (int j = 0; j < 1024; ++j) a += feat[j] * fc1_W[(size_t)j * HH + dcol];
    hid[dcol] = fmaxf(a, 0.f);
  }
  __syncthreads();

  float p0 = 0.f, p1 = 0.f, p2 = 0.f;
  for (int dv = tid; dv < 512; dv += 256) {
    const float hv = hid[dv];
    p0 += hv * fc2_W[dv * 3 + 0];
    p1 += hv * fc2_W[dv * 3 + 1];
    p2 += hv * fc2_W[dv * 3 + 2];
  }
  feat[tid] = p0; feat[256 + tid] = p1; feat[512 + tid] = p2;
  __syncthreads();
  for (int s = 128; s > 0; s >>= 1) {
    if (tid < s) {
      feat[tid] += feat[tid + s];
      feat[256 + tid] += feat[256 + tid + s];
      feat[512 + tid] += feat[512 + tid + s];
    }
    __syncthreads();
  }
  if (tid < 3) logits[b * 3 + tid] = feat[tid * 256] + fc2_b[tid];
}

// ---------------------------------------------------------------------------
extern "C" void kernel_launch(void* const* d_in, const int* in_sizes, int n_in,
                              void* d_out, int out_size, void* d_ws, size_t ws_size,
                              hipStream_t stream) {
  const int*   text  = (const int*)d_in[0];
  const int*   topic = (const int*)d_in[1];
  const float* emb   = (const float*)d_in[2];
  const float* tWz   = (const float*)d_in[3];
  const float* tbz   = (const float*)d_in[4];
  const float* tWo   = (const float*)d_in[5];
  const float* tbo   = (const float*)d_in[6];
  const float* pWz   = (const float*)d_in[7];
  const float* pbz   = (const float*)d_in[8];
  const float* pWo   = (const float*)d_in[9];
  const float* pbo   = (const float*)d_in[10];
  const float* attW  = (const float*)d_in[11];
  const float* attb  = (const float*)d_in[12];
  const float* fc1W  = (const float*)d_in[13];
  const float* fc1b  = (const float*)d_in[14];
  const float* fc2W  = (const float*)d_in[15];
  const float* fc2b  = (const float*)d_in[16];

  float* out = (float*)d_out;            // [0,192): logits, [192,+16384): weights
  float* ws  = (float*)d_ws;

  float* xp_text  = ws;                                    // 256*64*1024
  float* xp_topic = xp_text + (size_t)TTX * 64 * 1024;     // 16*64*1024
  float* text_o   = xp_topic + (size_t)TTP * 64 * 1024;    // 64*256*512
  float* topic_hv = text_o + (size_t)NB * TTX * HH;        // 64*512
  unsigned short* hring = (unsigned short*)(topic_hv + (size_t)NB * HH); // 4*64*512 bf16

  // bf16 fragment-order Bt buffers live in the text_o region (text|topic):
  // prep+xproj finish before sd_recur writes text_o (stream-serial) => safe.
  unsigned short* bt_text  = (unsigned short*)text_o;      // 327680 bf16
  unsigned short* bt_topic = bt_text + 327680;             // 327680 bf16

  sd_prep<<<dim3(2560), dim3(256), 0, stream>>>(tWz, tWo, pWz, pWo,
                                                bt_text, (unsigned*)hring);
  sd_xproj_mfma<<<dim3(TTX + TTP, 4), dim3(256), 0, stream>>>(
      text, topic, emb, bt_text, bt_topic, tbz, tbo, pbz, pbo, xp_text, xp_topic);
  sd_recur<<<dim3(128), dim3(512), 0, stream>>>(tWz, tWo, pWz, pWo, xp_text, xp_topic,
                                                text_o, hring, topic_hv);
  sd_att_fc<<<dim3(64), dim3(256), 0, stream>>>(text_o, topic_hv, attW, attb,
                                                fc1W, fc1b, fc2W, fc2b, out, out + 192);
}

// Round 12
// 639.527 us; speedup vs baseline: 1.1870x; 1.1870x over previous
//
#include <hip/hip_runtime.h>
#include <math.h>

#define NB 64      // batch
#define TTX 256    // text timesteps
#define TTP 16     // topic timesteps
#define EE 300     // embedding dim
#define HH 512     // hidden
#define SENT16 0x7FC1u        // bf16 NaN-payload sentinel (real h never NaN)
#define SENT32 0x7FC17FC1u
#define RINGW (4 * NB * HH)   // bf16 words per ring (4 slots)

typedef __attribute__((ext_vector_type(4))) float f32x4;
typedef __attribute__((ext_vector_type(8))) short short8;

__device__ __forceinline__ unsigned short bf16cvt(float f) {
  unsigned u = __float_as_uint(f);
  u += 0x7FFFu + ((u >> 16) & 1u);   // RNE
  return (unsigned short)(u >> 16);
}

// ---------------------------------------------------------------------------
// prep: (a) poison BOTH bf16 h-rings (text + topic; every call so graph
// replays are deterministic), (b) build Bt in FRAGMENT order (r10-verified).
// ---------------------------------------------------------------------------
__global__ __launch_bounds__(256) void sd_prep(
    const float* __restrict__ tWz, const float* __restrict__ tWo,
    const float* __restrict__ pWz, const float* __restrict__ pWo,
    unsigned short* __restrict__ Bt, unsigned* __restrict__ ring32)
{
  const int i = blockIdx.x * 256 + threadIdx.x;   // [0, 655360)
  if (i < RINGW) ring32[i] = SENT32;              // 2 rings = 131072 u32
  const int half = 327680;
  const int j = (i < half) ? i : i - half;
  const int e    = j & 7;
  const int lane = (j >> 3) & 63;
  const int kc   = (j >> 9) % 10;
  const int tile = (j >> 9) / 10;
  const int k = kc * 32 + 8 * (lane >> 4) + e;
  const int c = tile * 16 + (lane & 15);
  const float* W = (i < half) ? ((c < 512) ? tWz : tWo)
                              : ((c < 512) ? pWz : pWo);
  const float v = (k < 300) ? W[(size_t)k * HH + (c & 511)] : 0.f;
  Bt[i] = bf16cvt(v);
}

// ---------------------------------------------------------------------------
// xproj via MFMA bf16 (unchanged from round 10, verified)
// ---------------------------------------------------------------------------
__global__ __launch_bounds__(256) void sd_xproj_mfma(
    const int* __restrict__ text_idx, const int* __restrict__ topic_idx,
    const float* __restrict__ emb,
    const unsigned short* __restrict__ bt_text, const unsigned short* __restrict__ bt_topic,
    const float* __restrict__ tbz, const float* __restrict__ tbo,
    const float* __restrict__ pbz, const float* __restrict__ pbo,
    float* __restrict__ xp_text, float* __restrict__ xp_topic)
{
  __shared__ alignas(16) unsigned short Als[64 * 328];
  __shared__ int tok[64];

  const bool is_text = blockIdx.x < TTX;
  const int t   = is_text ? blockIdx.x : blockIdx.x - TTX;
  const int T   = is_text ? TTX : TTP;
  const int* idx = is_text ? text_idx : topic_idx;
  const unsigned short* Bt = is_text ? bt_text : bt_topic;
  const float* bz = is_text ? tbz : pbz;
  const float* bo = is_text ? tbo : pbo;
  float* xp = is_text ? xp_text : xp_topic;

  const int tid = threadIdx.x;
  const int c0  = blockIdx.y * 256;

  if (tid < 64) tok[tid] = idx[tid * T + t];
  __syncthreads();

  {
    const int m  = tid >> 2;
    const int qt = tid & 3;
    const float* er = emb + (size_t)tok[m] * EE;
    unsigned short* ar = Als + m * 328;
    for (int j = qt; j < 75; j += 4) {
      const float4 v = *(const float4*)(er + 4 * j);
      ushort4 o;
      o.x = bf16cvt(v.x); o.y = bf16cvt(v.y);
      o.z = bf16cvt(v.z); o.w = bf16cvt(v.w);
      *(ushort4*)(ar + 4 * j) = o;
    }
    if (qt == 0) {
      for (int k = 300; k < 328; ++k) ar[k] = 0;
    }
  }
  __syncthreads();

  const int w  = tid >> 6;
  const int l  = tid & 63;
  const int lr = l & 15;
  const int lg = l >> 4;
  const int tile0 = blockIdx.y * 16 + w * 4;   // this wave's first col-tile

  f32x4 acc[4][4];
#pragma unroll
  for (int ms = 0; ms < 4; ++ms)
#pragma unroll
    for (int ns = 0; ns < 4; ++ns)
      acc[ms][ns] = (f32x4){0.f, 0.f, 0.f, 0.f};

#pragma unroll 2
  for (int kc = 0; kc < 10; ++kc) {
    short8 bfr[4];
#pragma unroll
    for (int ns = 0; ns < 4; ++ns)
      bfr[ns] = *reinterpret_cast<const short8*>(
          Bt + (((size_t)(tile0 + ns) * 10 + kc) * 64 + l) * 8);
    short8 afr[4];
#pragma unroll
    for (int ms = 0; ms < 4; ++ms)
      afr[ms] = *reinterpret_cast<const short8*>(Als + (ms * 16 + lr) * 328 + kc * 32 + 8 * lg);
#pragma unroll
    for (int ms = 0; ms < 4; ++ms)
#pragma unroll
      for (int ns = 0; ns < 4; ++ns)
        acc[ms][ns] = __builtin_amdgcn_mfma_f32_16x16x32_bf16(afr[ms], bfr[ns], acc[ms][ns], 0, 0, 0);
  }

#pragma unroll
  for (int ns = 0; ns < 4; ++ns) {
    const int cg = c0 + w * 64 + ns * 16 + lr;
    const float bias = (cg < 512) ? bz[cg] : bo[cg - 512];
#pragma unroll
    for (int ms = 0; ms < 4; ++ms) {
#pragma unroll
      for (int r = 0; r < 4; ++r) {
        const int row = ms * 16 + lg * 4 + r;
        xp[((size_t)t * 64 + row) * 1024 + cg] = acc[ms][ns][r] + bias;
      }
    }
  }
}

// ---------------------------------------------------------------------------
// Persistent recurrence — EXACT r10 per-step structure (430us verified), but
// the two independent recurrences run CONCURRENTLY:
//   512 blocks = 2 chains x (16 batch-groups x 16 dim-slices).
//   bid <  256: text chain (T=256), ring 0, writes text_out.
//   bid >= 256: topic chain (T=16), ring 1, writes topic_h at t=T-1.
//   Co-residency: 2 blocks/CU (LDS 25KB, VGPR<=128 via launch_bounds(512,4),
//   16 waves/CU) -> all 512 blocks resident, spins safe. Chains never
//   interact; per-chain protocol/proofs identical to r10.
// ---------------------------------------------------------------------------
__global__ __launch_bounds__(512, 4) void sd_recur(
    const float* __restrict__ tWz, const float* __restrict__ tWo,
    const float* __restrict__ pWz, const float* __restrict__ pWo,
    const float* __restrict__ xp_text, const float* __restrict__ xp_topic,
    float* __restrict__ text_out, unsigned short* __restrict__ hring,
    float* __restrict__ topic_h)
{
  __shared__ alignas(16) unsigned short h_bf[2][2080];  // bf16 h, [4 rows][520]
  __shared__ alignas(16) float red[2][2048];            // [8 wv][4 row][64 col]

  const int tid = threadIdx.x;
  const int bid = blockIdx.x;
  const bool is_text = bid < 256;
  const int lbid = is_text ? bid : bid - 256;
  const int x = lbid & 7;          // XCD-ish (heuristic placement)
  const int q = lbid >> 3;
  const int g = x + 8 * (q >> 4);  // batch group 0..15
  const int slice = q & 15;        // dim slice 0..15
  const int b0 = g * 4;
  const int c_base = slice * 32;

  const float* Wz = is_text ? tWz : pWz;
  const float* Wo = is_text ? tWo : pWo;
  const float* xp = is_text ? xp_text : xp_topic;
  const int T = is_text ? TTX : TTP;
  unsigned short* ring = hring + (is_text ? 0 : RINGW);

  const int wv = tid >> 6;         // wave id = k-eighth (0..7)
  const int lane = tid & 63;
  const int lg = lane >> 4;        // k-slot group 0..3
  const int l15 = lane & 15;

  const int bi_w = tid >> 5;       // writer mapping (tid<128): batch row 0..3
  const int dw = tid & 31;

  // writer thread's ring offset within a slot (bf16 units)
  const size_t wslot_off = (size_t)(b0 + bi_w) * HH + c_base + dw;

  // --- prep W h-part bf16 B-fragments (once) ----------------------------
  short8 wfrag[4][2];
#pragma unroll
  for (int ns = 0; ns < 4; ++ns) {
    const float* Wg = (ns < 2) ? Wz : Wo;
    const int dim = (ns & 1) * 16 + l15;
#pragma unroll
    for (int kc = 0; kc < 2; ++kc) {
      const int kb = wv * 64 + kc * 32 + 8 * lg;
      short8 f;
#pragma unroll
      for (int e = 0; e < 8; ++e)
        f[e] = (short)bf16cvt(Wg[(size_t)(EE + kb + e) * HH + c_base + dim]);
      wfrag[ns][kc] = f;
    }
  }

  float hprev_r = 0.f;  // writer's own h (fp32-exact)

  for (int t = 0; t < T; ++t) {
    const int u = t;
    const int cur = u & 1;
    const bool do_poll = (u > 0);

    float xpz = 0.f, xpo = 0.f;
    if (tid < 128) {
      const float* xpr = xp + ((size_t)t * 64 + (b0 + bi_w)) * 1024 + c_base + dw;
      xpz = xpr[0];
      xpo = xpr[512];
    }

    if (do_poll) {
      // block-wide poll-stage: one u64 (4 bf16) per thread
      const unsigned long long* src64 = (const unsigned long long*)
          (ring + (size_t)(u & 3) * NB * HH + (size_t)b0 * HH);
      unsigned long long v;
      for (;;) {
        v = __hip_atomic_load(src64 + tid, __ATOMIC_RELAXED, __HIP_MEMORY_SCOPE_AGENT);
        const unsigned lo = (unsigned)v, hi = (unsigned)(v >> 32);
        if ((lo & 0xFFFFu) != SENT16 && (lo >> 16) != SENT16 &&
            (hi & 0xFFFFu) != SENT16 && (hi >> 16) != SENT16) break;
        __builtin_amdgcn_s_sleep(1);
      }
      *(unsigned long long*)&h_bf[cur][(tid >> 7) * 520 + (tid & 127) * 4] = v;
    }

    __syncthreads();  // whole block's poll complete + stage visible

    // Safe to recycle slot (u-1)&3 now (poll success => consumers done).
    if (do_poll && tid < 128 && !(tid & 1))
      __hip_atomic_store((unsigned*)(ring + (size_t)((u - 1) & 3) * NB * HH + wslot_off),
                         SENT32, __ATOMIC_RELAXED, __HIP_MEMORY_SCOPE_AGENT);

    if (do_poll) {
      const unsigned short* hb = &h_bf[cur][(lane & 3) * 520 + wv * 64 + 8 * lg];
      const short8 a0 = *reinterpret_cast<const short8*>(hb + 0);
      const short8 a1 = *reinterpret_cast<const short8*>(hb + 32);

      f32x4 acc[4];
#pragma unroll
      for (int ns = 0; ns < 4; ++ns) {
        acc[ns] = (f32x4){0.f, 0.f, 0.f, 0.f};
        acc[ns] = __builtin_amdgcn_mfma_f32_16x16x32_bf16(a0, wfrag[ns][0], acc[ns], 0, 0, 0);
        acc[ns] = __builtin_amdgcn_mfma_f32_16x16x32_bf16(a1, wfrag[ns][1], acc[ns], 0, 0, 0);
      }
      if (lane < 16) {
#pragma unroll
        for (int ns = 0; ns < 4; ++ns)
#pragma unroll
          for (int r = 0; r < 4; ++r)
            red[cur][wv * 256 + r * 64 + ns * 16 + lane] = acc[ns][r];
      }
    }

    __syncthreads();  // partials visible

    if (tid < 128) {
      float zp = 0.f, op = 0.f;
      if (do_poll) {
#pragma unroll
        for (int k2 = 0; k2 < 8; ++k2) {
          zp += red[cur][k2 * 256 + bi_w * 64 + dw];        // gate z
          op += red[cur][k2 * 256 + bi_w * 64 + 32 + dw];   // gate o
        }
      }
      const float a = zp + xpz;
      const float z = 1.f / (1.f + __expf(-a));
      const float bv = op + xpo;
      const float ab = fabsf(bv);
      const float e2 = __expf(-2.f * ab);
      const float htl = __builtin_copysignf((1.f - e2) / (1.f + e2), bv);
      const float hn = (1.f - z) * hprev_r + z * htl;
      hprev_r = hn;

      // pack 2 bf16 per lane pair; even thread stores one sc1 dword
      const unsigned short hb16 = bf16cvt(hn);
      const unsigned packed = (unsigned)hb16 |
                              ((unsigned)__shfl_down((int)hb16, 1, 64) << 16);

      // drain everything EXCEPT this step's own poison (per-wave counter)
      asm volatile("s_waitcnt vmcnt(1)" ::: "memory");
      if (!(tid & 1))
        __hip_atomic_store((unsigned*)(ring + (size_t)((u + 1) & 3) * NB * HH + wslot_off),
                           packed, __ATOMIC_RELAXED, __HIP_MEMORY_SCOPE_AGENT);
      if (is_text)
        text_out[((size_t)(b0 + bi_w) * TTX + t) * HH + c_base + dw] = hn;
      else if (t == T - 1)
        topic_h[(size_t)(b0 + bi_w) * HH + c_base + dw] = hn;
    }
    // no trailing barrier: 2-deep buffers tolerate one-phase skew
  }
}

// ---------------------------------------------------------------------------
// attention + FC head fused (unchanged from round 9/10, verified)
// ---------------------------------------------------------------------------
__global__ __launch_bounds__(256) void sd_att_fc(
    const float* __restrict__ text_out, const float* __restrict__ topic_h,
    const float* __restrict__ att_W, const float* __restrict__ att_b,
    const float* __restrict__ fc1_W, const float* __restrict__ fc1_b,
    const float* __restrict__ fc2_W, const float* __restrict__ fc2_b,
    float* __restrict__ logits, float* __restrict__ weights_out)
{
  __shared__ alignas(16) float aw[1024];
  __shared__ alignas(16) float th[512];
  __shared__ float sc_s[256];
  __shared__ float sred[256];
  __shared__ float wsh[256];
  __shared__ alignas(16) float feat[1024];
  __shared__ float hid[512];
  const int b = blockIdx.x, tid = threadIdx.x;

  for (int i = tid; i < 1024; i += 256) aw[i] = att_W[i];
  for (int i = tid; i < 512; i += 256) th[i] = topic_h[(size_t)b * HH + i];
  __syncthreads();

  float part = 0.f;
  for (int i = tid; i < 512; i += 256) part += th[i] * aw[512 + i];
  sred[tid] = part;
  __syncthreads();
  for (int s = 128; s > 0; s >>= 1) { if (tid < s) sred[tid] += sred[tid + s]; __syncthreads(); }
  const float cb = sred[0] + att_b[0];
  __syncthreads();

  const int gr = tid >> 5, ln = tid & 31;
  for (int rep = 0; rep < 32; ++rep) {
    const int t = rep * 8 + gr;
    const float* row = text_out + ((size_t)b * TTX + t) * HH;
    float p = 0.f;
#pragma unroll
    for (int j = 0; j < 4; ++j) {
      const float4 v  = *(const float4*)(row + ln * 4 + 128 * j);
      const float4 w4 = *(const float4*)(aw  + ln * 4 + 128 * j);
      p += v.x * w4.x + v.y * w4.y + v.z * w4.z + v.w * w4.w;
    }
#pragma unroll
    for (int o = 16; o > 0; o >>= 1) p += __shfl_xor(p, o, 32);
    if (ln == 0) sc_s[t] = p + cb;
  }
  __syncthreads();

  const float sc = sc_s[tid];
  sred[tid] = sc; __syncthreads();
  for (int s = 128; s > 0; s >>= 1) { if (tid < s) sred[tid] = fmaxf(sred[tid], sred[tid + s]); __syncthreads(); }
  const float m = sred[0];
  __syncthreads();
  const float e = expf(sc - m);
  sred[tid] = e; __syncthreads();
  for (int s = 128; s > 0; s >>= 1) { if (tid < s) sred[tid] += sred[tid + s]; __syncthreads(); }
  const float wv = e / sred[0];
  wsh[tid] = wv;
  weights_out[(size_t)b * TTX + tid] = wv;
  __syncthreads();

  for (int rep = 0; rep < 2; ++rep) {
    const int dcol = rep * 256 + tid;
    float accc = 0.f;
    const float* base = text_out + (size_t)b * TTX * HH + dcol;
    for (int t2 = 0; t2 < TTX; ++t2) accc += wsh[t2] * base[(size_t)t2 * HH];
    feat[dcol] = accc;
  }
  for (int i = tid; i < 512; i += 256) feat[512 + i] = th[i];
  __syncthreads();

  for (int rep = 0; rep < 2; ++rep) {
    const int dcol = rep * 256 + tid;
    float a = fc1_b[dcol];
#pragma unroll 4
    for (int j = 0; j < 1024; ++j) a += feat[j] * fc1_W[(size_t)j * HH + dcol];
    hid[dcol] = fmaxf(a, 0.f);
  }
  __syncthreads();

  float p0 = 0.f, p1 = 0.f, p2 = 0.f;
  for (int dv = tid; dv < 512; dv += 256) {
    const float hv = hid[dv];
    p0 += hv * fc2_W[dv * 3 + 0];
    p1 += hv * fc2_W[dv * 3 + 1];
    p2 += hv * fc2_W[dv * 3 + 2];
  }
  feat[tid] = p0; feat[256 + tid] = p1; feat[512 + tid] = p2;
  __syncthreads();
  for (int s = 128; s > 0; s >>= 1) {
    if (tid < s) {
      feat[tid] += feat[tid + s];
      feat[256 + tid] += feat[256 + tid + s];
      feat[512 + tid] += feat[512 + tid + s];
    }
    __syncthreads();
  }
  if (tid < 3) logits[b * 3 + tid] = feat[tid * 256] + fc2_b[tid];
}

// ---------------------------------------------------------------------------
extern "C" void kernel_launch(void* const* d_in, const int* in_sizes, int n_in,
                              void* d_out, int out_size, void* d_ws, size_t ws_size,
                              hipStream_t stream) {
  const int*   text  = (const int*)d_in[0];
  const int*   topic = (const int*)d_in[1];
  const float* emb   = (const float*)d_in[2];
  const float* tWz   = (const float*)d_in[3];
  const float* tbz   = (const float*)d_in[4];
  const float* tWo   = (const float*)d_in[5];
  const float* tbo   = (const float*)d_in[6];
  const float* pWz   = (const float*)d_in[7];
  const float* pbz   = (const float*)d_in[8];
  const float* pWo   = (const float*)d_in[9];
  const float* pbo   = (const float*)d_in[10];
  const float* attW  = (const float*)d_in[11];
  const float* attb  = (const float*)d_in[12];
  const float* fc1W  = (const float*)d_in[13];
  const float* fc1b  = (const float*)d_in[14];
  const float* fc2W  = (const float*)d_in[15];
  const float* fc2b  = (const float*)d_in[16];

  float* out = (float*)d_out;            // [0,192): logits, [192,+16384): weights
  float* ws  = (float*)d_ws;

  float* xp_text  = ws;                                    // 256*64*1024
  float* xp_topic = xp_text + (size_t)TTX * 64 * 1024;     // 16*64*1024
  float* text_o   = xp_topic + (size_t)TTP * 64 * 1024;    // 64*256*512
  float* topic_hv = text_o + (size_t)NB * TTX * HH;        // 64*512
  unsigned short* hring = (unsigned short*)(topic_hv + (size_t)NB * HH); // 2 rings x 4*64*512 bf16

  // bf16 fragment-order Bt buffers live in the text_o region (text|topic):
  // prep+xproj finish before sd_recur writes text_o (stream-serial) => safe.
  unsigned short* bt_text  = (unsigned short*)text_o;      // 327680 bf16
  unsigned short* bt_topic = bt_text + 327680;             // 327680 bf16

  sd_prep<<<dim3(2560), dim3(256), 0, stream>>>(tWz, tWo, pWz, pWo,
                                                bt_text, (unsigned*)hring);
  sd_xproj_mfma<<<dim3(TTX + TTP, 4), dim3(256), 0, stream>>>(
      text, topic, emb, bt_text, bt_topic, tbz, tbo, pbz, pbo, xp_text, xp_topic);
  sd_recur<<<dim3(512), dim3(512), 0, stream>>>(tWz, tWo, pWz, pWo, xp_text, xp_topic,
                                                text_o, hring, topic_hv);
  sd_att_fc<<<dim3(64), dim3(256), 0, stream>>>(text_o, topic_hv, attW, attb,
                                                fc1W, fc1b, fc2W, fc2b, out, out + 192);
}